// Round 7
// baseline (609.699 us; speedup 1.0000x reference)
//
#include <hip/hip_runtime.h>
#include <hip/hip_fp16.h>
#include <math.h>

#define N_NODES 100000
#define N_EDGES 1250000
#define D 64
#define EPS 1e-8f

#define GEMM_BLOCKS 1024
#define NODE_BLOCKS 512          // persistent kernel; 2 blocks/CU worst-case -> always co-resident
#define NODE_GROUPS (NODE_BLOCKS * 256 / 16)   // 8192 16-lane groups

// ---------------------------------------------------------------------------
// zero cnt[100000] + bar[16] (contiguous)
// ---------------------------------------------------------------------------
__global__ void k_zero(int* __restrict__ cnt)
{
    int i = blockIdx.x * 256 + threadIdx.x;
    if (i < N_NODES + 16) cnt[i] = 0;
}

// ---------------------------------------------------------------------------
// Fused: blocks [0,GEMM_BLOCKS) do gemm+normalize -> fp16 hn (persistent);
// blocks [GEMM_BLOCKS, ...) do the rank pass (the ONLY scattered atomics).
// Independent work, one dispatch, co-scheduled on the CUs.
// ---------------------------------------------------------------------------
__global__ __launch_bounds__(256) void k_gemm_rank(
    const float* __restrict__ x, const float* __restrict__ W,
    const float* __restrict__ b, __half* __restrict__ hn,
    const int* __restrict__ ei, int* __restrict__ cnt, int* __restrict__ rank)
{
    if (blockIdx.x >= GEMM_BLOCKS) {
        int e = (blockIdx.x - GEMM_BLOCKS) * 256 + threadIdx.x;
        if (e < N_EDGES) {
            int d = ei[N_EDGES + e];
            rank[e] = atomicAdd(cnt + d, 1);
        }
        return;
    }

    __shared__ float xrow[4][72];
    const int lane = threadIdx.x & 63;
    const int wid  = threadIdx.x >> 6;

    float Wreg[64];
    const float4* Wv = (const float4*)(W + lane * D);
    #pragma unroll
    for (int q = 0; q < 16; ++q) {
        float4 w4 = Wv[q];
        Wreg[4*q+0] = w4.x; Wreg[4*q+1] = w4.y;
        Wreg[4*q+2] = w4.z; Wreg[4*q+3] = w4.w;
    }
    const float bj = b[lane];
    float* xl = xrow[wid];

    const int wave   = blockIdx.x * 4 + wid;
    const int nwaves = GEMM_BLOCKS * 4;

    for (int row = wave; row < N_NODES; row += nwaves) {
        float xv = x[(size_t)row * D + lane];
        xl[lane] = xv;
        float acc = bj;
        #pragma unroll
        for (int q = 0; q < 16; ++q) {
            float4 xk4 = *(const float4*)(xl + 4*q);
            acc = fmaf(xk4.x, Wreg[4*q+0], acc);
            acc = fmaf(xk4.y, Wreg[4*q+1], acc);
            acc = fmaf(xk4.z, Wreg[4*q+2], acc);
            acc = fmaf(xk4.w, Wreg[4*q+3], acc);
        }
        float h = tanhf(acc);
        float s = h * h;
        #pragma unroll
        for (int m = 32; m >= 1; m >>= 1) s += __shfl_xor(s, m, 64);
        float nrm = fmaxf(sqrtf(s), EPS);
        hn[(size_t)row * D + lane] = __float2half_rn(h / nrm);
    }
}

// ---------------------------------------------------------------------------
// Scan: exclusive prefix sum of cnt[100000] -> rowptr (3 small kernels)
// ---------------------------------------------------------------------------
__device__ __forceinline__ int wave_iscan(int v, int lane)
{
    int incl = v;
    #pragma unroll
    for (int m = 1; m < 64; m <<= 1) {
        int o = __shfl_up(incl, m, 64);
        if (lane >= m) incl += o;
    }
    return incl;
}

__global__ __launch_bounds__(256) void k_scan1(
    const int* __restrict__ cnt, int* __restrict__ rowptr, int* __restrict__ bsum)
{
    __shared__ int wsum[4];
    int t = threadIdx.x, b = blockIdx.x;
    int i = b * 256 + t;
    int lane = t & 63, wid = t >> 6;
    int v = (i < N_NODES) ? cnt[i] : 0;
    int incl = wave_iscan(v, lane);
    if (lane == 63) wsum[wid] = incl;
    __syncthreads();
    int off = 0;
    #pragma unroll
    for (int k = 0; k < 4; ++k) if (k < wid) off += wsum[k];
    if (i < N_NODES) rowptr[i] = off + incl - v;
    if (t == 255) bsum[b] = off + incl;
}

__global__ __launch_bounds__(512) void k_scan2(
    const int* __restrict__ bsum, int* __restrict__ boff, int nblk)
{
    __shared__ int wsum[8];
    int t = threadIdx.x;
    int lane = t & 63, wid = t >> 6;
    int v = (t < nblk) ? bsum[t] : 0;
    int incl = wave_iscan(v, lane);
    if (lane == 63) wsum[wid] = incl;
    __syncthreads();
    int off = 0;
    #pragma unroll
    for (int k = 0; k < 8; ++k) if (k < wid) off += wsum[k];
    if (t < nblk) boff[t] = off + incl - v;
}

__global__ __launch_bounds__(256) void k_scan3(
    int* __restrict__ rowptr, const int* __restrict__ boff)
{
    int i = blockIdx.x * 256 + threadIdx.x;
    if (i < N_NODES) rowptr[i] += boff[i >> 8];
    if (i == 0) rowptr[N_NODES] = N_EDGES;
}

// ---------------------------------------------------------------------------
// Fused cosine + CSR placement. ZERO atomics. 8 lanes/edge, 4 edges/thread.
// ---------------------------------------------------------------------------
__device__ __forceinline__ float dot8h(float4 a, float4 c)
{
    const __half2* ah = (const __half2*)&a;
    const __half2* ch = (const __half2*)&c;
    float p = 0.0f;
    #pragma unroll
    for (int q = 0; q < 4; ++q) {
        float2 af = __half22float2(ah[q]);
        float2 cf = __half22float2(ch[q]);
        p = fmaf(af.x, cf.x, p);
        p = fmaf(af.y, cf.y, p);
    }
    return p;
}

__global__ __launch_bounds__(256) void k_edge_place(
    const __half* __restrict__ hn, const int* __restrict__ ei,
    const int* __restrict__ rank, const int* __restrict__ rowptr,
    float* __restrict__ wout, int2* __restrict__ pairs)
{
    int t = blockIdx.x * 256 + threadIdx.x;
    int g = t >> 3, sub = t & 7;
    if (g >= N_EDGES / 4) return;
    int e0 = g * 4;
    int4 ss = *(const int4*)(ei + e0);
    int4 dd = *(const int4*)(ei + N_EDGES + e0);

    float4 a0 = ((const float4*)(hn + (size_t)ss.x * D))[sub];
    float4 c0 = ((const float4*)(hn + (size_t)dd.x * D))[sub];
    float4 a1 = ((const float4*)(hn + (size_t)ss.y * D))[sub];
    float4 c1 = ((const float4*)(hn + (size_t)dd.y * D))[sub];
    float4 a2 = ((const float4*)(hn + (size_t)ss.z * D))[sub];
    float4 c2 = ((const float4*)(hn + (size_t)dd.z * D))[sub];
    float4 a3 = ((const float4*)(hn + (size_t)ss.w * D))[sub];
    float4 c3 = ((const float4*)(hn + (size_t)dd.w * D))[sub];

    float p0 = dot8h(a0, c0);
    float p1 = dot8h(a1, c1);
    float p2 = dot8h(a2, c2);
    float p3 = dot8h(a3, c3);
    p0 += __shfl_xor(p0, 1, 64);  p1 += __shfl_xor(p1, 1, 64);
    p2 += __shfl_xor(p2, 1, 64);  p3 += __shfl_xor(p3, 1, 64);
    p0 += __shfl_xor(p0, 2, 64);  p1 += __shfl_xor(p1, 2, 64);
    p2 += __shfl_xor(p2, 2, 64);  p3 += __shfl_xor(p3, 2, 64);
    p0 += __shfl_xor(p0, 4, 64);  p1 += __shfl_xor(p1, 4, 64);
    p2 += __shfl_xor(p2, 4, 64);  p3 += __shfl_xor(p3, 4, 64);

    if (sub == 0) {
        float w0 = fmaxf(p0, 0.0f);
        float w1 = fmaxf(p1, 0.0f);
        float w2 = fmaxf(p2, 0.0f);
        float w3 = fmaxf(p3, 0.0f);
        *(float4*)(wout + e0) = make_float4(w0, w1, w2, w3);
        int4 rk = *(const int4*)(rank + e0);
        int pos0 = rowptr[dd.x] + rk.x;
        int pos1 = rowptr[dd.y] + rk.y;
        int pos2 = rowptr[dd.z] + rk.z;
        int pos3 = rowptr[dd.w] + rk.w;
        int2 pr;
        pr.x = ss.x; pr.y = __float_as_int(w0); pairs[pos0] = pr;
        pr.x = ss.y; pr.y = __float_as_int(w1); pairs[pos1] = pr;
        pr.x = ss.z; pr.y = __float_as_int(w2); pairs[pos2] = pr;
        pr.x = ss.w; pr.y = __float_as_int(w3); pairs[pos3] = pr;
    }
}

// ---------------------------------------------------------------------------
// Device-scope grid barrier (cooperative-groups pattern, XCD-coherence safe):
// release fence + device atomic signal; acquire-spin invalidates stale L2.
// ---------------------------------------------------------------------------
__device__ __forceinline__ void gsync(int* bar, int idx, int nblk)
{
    __syncthreads();
    if (threadIdx.x == 0) {
        __threadfence();                                   // agent-scope release
        atomicAdd(bar + idx, 1);
        while (__hip_atomic_load(bar + idx, __ATOMIC_ACQUIRE,
                                 __HIP_MEMORY_SCOPE_AGENT) < nblk) {
            __builtin_amdgcn_s_sleep(8);
        }
    }
    __syncthreads();
}

// ---------------------------------------------------------------------------
// Persistent node kernel: dis/y0 init, then 5 APPNP steps with grid barriers.
// 16 lanes per node-group, grid-stride over nodes. Final step writes d_out.
// ---------------------------------------------------------------------------
__global__ __launch_bounds__(256) void k_node(
    const int* __restrict__ rowptr, const int2* __restrict__ pairs,
    const float* __restrict__ mask, const float* __restrict__ alpha_p,
    float* __restrict__ dis, float* y_a, float* y_b,
    int* __restrict__ bar, float* __restrict__ out_f)
{
    const int t    = blockIdx.x * 256 + threadIdx.x;
    const int gid  = t >> 4;
    const int l    = t & 15;
    const float alpha = alpha_p[0];

    // Phase 0: deg segment-sum -> dis, y0 = dis*relu(mask)
    for (int node = gid; node < N_NODES; node += NODE_GROUPS) {
        int beg = rowptr[node], end = rowptr[node + 1];
        float s = 0.0f;
        for (int j = beg + l; j < end; j += 16)
            s += __int_as_float(pairs[j].y);
        s += __shfl_xor(s, 1, 64);
        s += __shfl_xor(s, 2, 64);
        s += __shfl_xor(s, 4, 64);
        s += __shfl_xor(s, 8, 64);
        if (l == 0) {
            float di = rsqrtf(fmaxf(s + 1.0f, EPS));   // +1 self-loop
            dis[node] = di;
            y_a[node] = di * fmaxf(mask[node], 0.0f);
        }
    }
    gsync(bar, 0, NODE_BLOCKS);

    // Phases 1..5: APPNP steps in y-domain
    for (int step = 0; step < 5; ++step) {
        const float* yin = (step & 1) ? y_b : y_a;
        float*       yout = (step & 1) ? y_a : y_b;
        for (int node = gid; node < N_NODES; node += NODE_GROUPS) {
            int beg = rowptr[node], end = rowptr[node + 1];
            float sum = 0.0f;
            for (int j = beg + l; j < end; j += 16) {
                int2 p = pairs[j];
                sum += __int_as_float(p.y) * yin[p.x];
            }
            sum += __shfl_xor(sum, 1, 64);
            sum += __shfl_xor(sum, 2, 64);
            sum += __shfl_xor(sum, 4, 64);
            sum += __shfl_xor(sum, 8, 64);
            if (l == 0) {
                float di = dis[node];
                float f0 = fmaxf(mask[node], 0.0f);
                float fn = (1.0f - alpha) * di * (sum + yin[node]) + alpha * f0;
                if (step == 4) out_f[node] = fn;
                else           yout[node] = di * fn;
            }
        }
        if (step < 4) gsync(bar, 1 + step, NODE_BLOCKS);
    }
}

extern "C" void kernel_launch(void* const* d_in, const int* in_sizes, int n_in,
                              void* d_out, int out_size, void* d_ws, size_t ws_size,
                              hipStream_t stream)
{
    const float* x     = (const float*)d_in[0];
    const float* mask  = (const float*)d_in[1];
    const int*   ei    = (const int*)  d_in[2];
    const float* W     = (const float*)d_in[3];
    const float* b     = (const float*)d_in[4];
    const float* alpha = (const float*)d_in[5];

    float* out_f = (float*)d_out;
    float* out_w = (float*)d_out + N_NODES;

    // workspace layout (float-element offsets); bar MUST follow cnt (zeroed together)
    float* ws = (float*)d_ws;
    __half* hn     = (__half*)ws;                  // 6.4M halves
    int2*  pairs   = (int2*) (ws + 3200000);       // 1.25M x 8B
    int*   rank    = (int*)  (ws + 5700000);       // 1.25M
    int*   cnt     = (int*)  (ws + 6950000);       // 100k
    int*   bar     = (int*)  (ws + 7050000);       // 16
    int*   rowptr  = (int*)  (ws + 7050016);       // 100001 (alloc 100016)
    float* dis     =          ws + 7150032;        // 100k
    float* y_a     =          ws + 7250032;        // 100k
    float* y_b     =          ws + 7350032;        // 100k
    int*   bsum    = (int*)  (ws + 7450032);       // 391 (alloc 512)
    int*   boff    = (int*)  (ws + 7450544);       // 391

    const int nodeBlocks  = (N_NODES + 255) / 256;                       // 391
    const int edgeBlocks  = (N_EDGES + 255) / 256;                       // 4883
    const int zeroBlocks  = (N_NODES + 16 + 255) / 256;
    const int placeBlocks = (int)(((long long)(N_EDGES / 4) * 8 + 255) / 256);  // 9766

    k_zero<<<zeroBlocks, 256, 0, stream>>>(cnt);
    k_gemm_rank<<<GEMM_BLOCKS + edgeBlocks, 256, 0, stream>>>(x, W, b, hn, ei, cnt, rank);
    k_scan1<<<nodeBlocks, 256, 0, stream>>>(cnt, rowptr, bsum);
    k_scan2<<<1, 512, 0, stream>>>(bsum, boff, nodeBlocks);
    k_scan3<<<nodeBlocks, 256, 0, stream>>>(rowptr, boff);
    k_edge_place<<<placeBlocks, 256, 0, stream>>>(hn, ei, rank, rowptr, out_w, pairs);
    k_node<<<NODE_BLOCKS, 256, 0, stream>>>(rowptr, pairs, mask, alpha, dis, y_a, y_b, bar, out_f);
}

// Round 8
// 300.250 us; speedup vs baseline: 2.0306x; 2.0306x over previous
//
#include <hip/hip_runtime.h>
#include <hip/hip_fp16.h>
#include <math.h>

#define N_NODES 100000
#define N_EDGES 1250000
#define D 64
#define EPS 1e-8f
#define GEMM_BLOCKS 2048

// ---------------------------------------------------------------------------
// Kernel 1: hn[i,:] = normalize(tanh(x[i,:] @ W^T + b)) -> fp16
// 2048 blocks, 2 rows per wave iteration (2 independent latency chains).
// ---------------------------------------------------------------------------
__global__ __launch_bounds__(256) void k_gemm_norm(
    const float* __restrict__ x, const float* __restrict__ W,
    const float* __restrict__ b, __half* __restrict__ hn)
{
    __shared__ float xrow[4][160];
    const int lane = threadIdx.x & 63;
    const int wid  = threadIdx.x >> 6;

    float Wreg[64];
    const float4* Wv = (const float4*)(W + lane * D);
    #pragma unroll
    for (int q = 0; q < 16; ++q) {
        float4 w4 = Wv[q];
        Wreg[4*q+0] = w4.x; Wreg[4*q+1] = w4.y;
        Wreg[4*q+2] = w4.z; Wreg[4*q+3] = w4.w;
    }
    const float bj = b[lane];
    float* xl = xrow[wid];

    const int wave   = blockIdx.x * 4 + wid;
    const int nwaves = GEMM_BLOCKS * 4;

    for (int row = wave * 2; row < N_NODES; row += nwaves * 2) {
        const int row1 = row + 1;                      // N_NODES even -> in range
        float xv0 = x[(size_t)row  * D + lane];
        float xv1 = x[(size_t)row1 * D + lane];
        xl[lane]      = xv0;
        xl[80 + lane] = xv1;
        float acc0 = bj, acc1 = bj;
        #pragma unroll
        for (int q = 0; q < 16; ++q) {
            float4 xa = *(const float4*)(xl + 4*q);
            float4 xb = *(const float4*)(xl + 80 + 4*q);
            acc0 = fmaf(xa.x, Wreg[4*q+0], acc0);
            acc1 = fmaf(xb.x, Wreg[4*q+0], acc1);
            acc0 = fmaf(xa.y, Wreg[4*q+1], acc0);
            acc1 = fmaf(xb.y, Wreg[4*q+1], acc1);
            acc0 = fmaf(xa.z, Wreg[4*q+2], acc0);
            acc1 = fmaf(xb.z, Wreg[4*q+2], acc1);
            acc0 = fmaf(xa.w, Wreg[4*q+3], acc0);
            acc1 = fmaf(xb.w, Wreg[4*q+3], acc1);
        }
        float h0 = tanhf(acc0);
        float h1 = tanhf(acc1);
        float s0 = h0 * h0, s1 = h1 * h1;
        #pragma unroll
        for (int m = 32; m >= 1; m >>= 1) {
            s0 += __shfl_xor(s0, m, 64);
            s1 += __shfl_xor(s1, m, 64);
        }
        hn[(size_t)row  * D + lane] = __float2half_rn(h0 / fmaxf(sqrtf(s0), EPS));
        hn[(size_t)row1 * D + lane] = __float2half_rn(h1 / fmaxf(sqrtf(s1), EPS));
    }
}

__global__ void k_zero(int* __restrict__ cnt)
{
    int i = blockIdx.x * 256 + threadIdx.x;
    if (i < N_NODES) cnt[i] = 0;
}

// ---------------------------------------------------------------------------
// The ONLY atomic pass: per-edge rank within its destination node.
// ---------------------------------------------------------------------------
__global__ void k_rank(const int* __restrict__ ei, int* __restrict__ cnt,
                       int* __restrict__ rank)
{
    int e = blockIdx.x * 256 + threadIdx.x;
    if (e >= N_EDGES) return;
    int d = ei[N_EDGES + e];
    rank[e] = atomicAdd(cnt + d, 1);
}

// ---------------------------------------------------------------------------
// Scan: exclusive prefix sum of cnt[100000] -> rowptr (2 kernels)
// ---------------------------------------------------------------------------
__device__ __forceinline__ int wave_iscan(int v, int lane)
{
    int incl = v;
    #pragma unroll
    for (int m = 1; m < 64; m <<= 1) {
        int o = __shfl_up(incl, m, 64);
        if (lane >= m) incl += o;
    }
    return incl;
}

__global__ __launch_bounds__(256) void k_scan1(
    const int* __restrict__ cnt, int* __restrict__ rowptr, int* __restrict__ bsum)
{
    __shared__ int wsum[4];
    int t = threadIdx.x, b = blockIdx.x;
    int i = b * 256 + t;
    int lane = t & 63, wid = t >> 6;
    int v = (i < N_NODES) ? cnt[i] : 0;
    int incl = wave_iscan(v, lane);
    if (lane == 63) wsum[wid] = incl;
    __syncthreads();
    int off = 0;
    #pragma unroll
    for (int k = 0; k < 4; ++k) if (k < wid) off += wsum[k];
    if (i < N_NODES) rowptr[i] = off + incl - v;
    if (t == 255) bsum[b] = off + incl;
}

// Fused scan2+scan3: block b sums bsum[0..b-1] itself, applies to rowptr.
__global__ __launch_bounds__(256) void k_scan23(
    int* __restrict__ rowptr, const int* __restrict__ bsum)
{
    __shared__ int wred[4];
    int b = blockIdx.x, t = threadIdx.x;
    int partial = 0;
    for (int j = t; j < b; j += 256) partial += bsum[j];
    #pragma unroll
    for (int m = 1; m < 64; m <<= 1) partial += __shfl_xor(partial, m, 64);
    if ((t & 63) == 0) wred[t >> 6] = partial;
    __syncthreads();
    int boff = wred[0] + wred[1] + wred[2] + wred[3];
    int i = b * 256 + t;
    if (i < N_NODES) rowptr[i] += boff;
    if (i == 0) rowptr[N_NODES] = N_EDGES;
}

// ---------------------------------------------------------------------------
// Fused cosine + CSR placement. ZERO atomics. 8 lanes/edge, 4 edges/thread.
// Writes split CSR: srcs[] (int) + wh[] (fp16 raw relu-cos weight).
// ---------------------------------------------------------------------------
__device__ __forceinline__ float dot8h(float4 a, float4 c)
{
    const __half2* ah = (const __half2*)&a;
    const __half2* ch = (const __half2*)&c;
    float p = 0.0f;
    #pragma unroll
    for (int q = 0; q < 4; ++q) {
        float2 af = __half22float2(ah[q]);
        float2 cf = __half22float2(ch[q]);
        p = fmaf(af.x, cf.x, p);
        p = fmaf(af.y, cf.y, p);
    }
    return p;
}

__global__ __launch_bounds__(256) void k_edge_place(
    const __half* __restrict__ hn, const int* __restrict__ ei,
    const int* __restrict__ rank, const int* __restrict__ rowptr,
    float* __restrict__ wout, int* __restrict__ srcs, __half* __restrict__ wh)
{
    int t = blockIdx.x * 256 + threadIdx.x;
    int g = t >> 3, sub = t & 7;
    if (g >= N_EDGES / 4) return;
    int e0 = g * 4;
    int4 ss = *(const int4*)(ei + e0);
    int4 dd = *(const int4*)(ei + N_EDGES + e0);

    float4 a0 = ((const float4*)(hn + (size_t)ss.x * D))[sub];
    float4 c0 = ((const float4*)(hn + (size_t)dd.x * D))[sub];
    float4 a1 = ((const float4*)(hn + (size_t)ss.y * D))[sub];
    float4 c1 = ((const float4*)(hn + (size_t)dd.y * D))[sub];
    float4 a2 = ((const float4*)(hn + (size_t)ss.z * D))[sub];
    float4 c2 = ((const float4*)(hn + (size_t)dd.z * D))[sub];
    float4 a3 = ((const float4*)(hn + (size_t)ss.w * D))[sub];
    float4 c3 = ((const float4*)(hn + (size_t)dd.w * D))[sub];

    float p0 = dot8h(a0, c0);
    float p1 = dot8h(a1, c1);
    float p2 = dot8h(a2, c2);
    float p3 = dot8h(a3, c3);
    p0 += __shfl_xor(p0, 1, 64);  p1 += __shfl_xor(p1, 1, 64);
    p2 += __shfl_xor(p2, 1, 64);  p3 += __shfl_xor(p3, 1, 64);
    p0 += __shfl_xor(p0, 2, 64);  p1 += __shfl_xor(p1, 2, 64);
    p2 += __shfl_xor(p2, 2, 64);  p3 += __shfl_xor(p3, 2, 64);
    p0 += __shfl_xor(p0, 4, 64);  p1 += __shfl_xor(p1, 4, 64);
    p2 += __shfl_xor(p2, 4, 64);  p3 += __shfl_xor(p3, 4, 64);

    if (sub == 0) {
        float w0 = fmaxf(p0, 0.0f);
        float w1 = fmaxf(p1, 0.0f);
        float w2 = fmaxf(p2, 0.0f);
        float w3 = fmaxf(p3, 0.0f);
        *(float4*)(wout + e0) = make_float4(w0, w1, w2, w3);
        int4 rk = *(const int4*)(rank + e0);
        int pos0 = rowptr[dd.x] + rk.x;
        int pos1 = rowptr[dd.y] + rk.y;
        int pos2 = rowptr[dd.z] + rk.z;
        int pos3 = rowptr[dd.w] + rk.w;
        srcs[pos0] = ss.x;  wh[pos0] = __float2half_rn(w0);
        srcs[pos1] = ss.y;  wh[pos1] = __float2half_rn(w1);
        srcs[pos2] = ss.z;  wh[pos2] = __float2half_rn(w2);
        srcs[pos3] = ss.w;  wh[pos3] = __float2half_rn(w3);
    }
}

// ---------------------------------------------------------------------------
// deg via segment-sum of wh, 16 lanes/node; dis = rsqrt(deg); y0 = dis*relu(mask)
// ---------------------------------------------------------------------------
__global__ __launch_bounds__(256) void k_dis_y(
    const int* __restrict__ rowptr, const __half* __restrict__ wh,
    const float* __restrict__ mask, float* __restrict__ dis,
    float* __restrict__ y)
{
    int t = blockIdx.x * 256 + threadIdx.x;
    int node = t >> 4, l = t & 15;
    if (node >= N_NODES) return;
    int beg = rowptr[node], end = rowptr[node + 1];
    float s = 0.0f;
    for (int j = beg + l; j < end; j += 16)
        s += __half2float(wh[j]);
    s += __shfl_xor(s, 1, 64);
    s += __shfl_xor(s, 2, 64);
    s += __shfl_xor(s, 4, 64);
    s += __shfl_xor(s, 8, 64);
    if (l == 0) {
        float di = rsqrtf(fmaxf(s + 1.0f, EPS));   // +1 self-loop
        dis[node] = di;
        y[node] = di * fmaxf(mask[node], 0.0f);
    }
}

// ---------------------------------------------------------------------------
// APPNP step in y-domain, 16 lanes per node, no atomics:
// f'_i = (1-a) * dis_i * ( sum_j w_ij*y_j + y_i ) + a*relu(mask_i)
// ---------------------------------------------------------------------------
__global__ __launch_bounds__(256) void k_spmv(
    const int* __restrict__ rowptr, const int* __restrict__ srcs,
    const __half* __restrict__ wh, const float* __restrict__ y_in,
    const float* __restrict__ dis, const float* __restrict__ mask,
    const float* __restrict__ alpha_p, float* __restrict__ y_out,
    float* __restrict__ f_out)
{
    int t = blockIdx.x * 256 + threadIdx.x;
    int node = t >> 4, l = t & 15;
    if (node >= N_NODES) return;
    int beg = rowptr[node], end = rowptr[node + 1];
    float sum = 0.0f;
    for (int j = beg + l; j < end; j += 16)
        sum += __half2float(wh[j]) * y_in[srcs[j]];
    sum += __shfl_xor(sum, 1, 64);
    sum += __shfl_xor(sum, 2, 64);
    sum += __shfl_xor(sum, 4, 64);
    sum += __shfl_xor(sum, 8, 64);
    if (l == 0) {
        float di = dis[node];
        float alpha = alpha_p[0];
        float f0 = fmaxf(mask[node], 0.0f);
        float fn = (1.0f - alpha) * di * (sum + y_in[node]) + alpha * f0;
        f_out[node] = fn;
        y_out[node] = di * fn;
    }
}

extern "C" void kernel_launch(void* const* d_in, const int* in_sizes, int n_in,
                              void* d_out, int out_size, void* d_ws, size_t ws_size,
                              hipStream_t stream)
{
    const float* x     = (const float*)d_in[0];
    const float* mask  = (const float*)d_in[1];
    const int*   ei    = (const int*)  d_in[2];
    const float* W     = (const float*)d_in[3];
    const float* b     = (const float*)d_in[4];
    const float* alpha = (const float*)d_in[5];

    float* out_f = (float*)d_out;
    float* out_w = (float*)d_out + N_NODES;

    // workspace layout (float-element offsets), ~27.5 MB
    float* ws = (float*)d_ws;
    __half* hn     = (__half*)ws;                  // 6.4M halves
    int*   srcs    = (int*)   (ws + 3200000);      // 1.25M
    __half* wh     = (__half*)(ws + 4450000);      // 1.25M halves
    int*   rank    = (int*)   (ws + 5075000);      // 1.25M
    int*   cnt     = (int*)   (ws + 6325000);      // 100k
    int*   rowptr  = (int*)   (ws + 6425000);      // 100001 (alloc 100016)
    float* dis     =           ws + 6525016;       // 100k
    float* y_a     =           ws + 6625016;       // 100k
    float* y_b     =           ws + 6725016;       // 100k
    int*   bsum    = (int*)   (ws + 6825016);      // 391 (alloc 512)

    const int nodeBlocks  = (N_NODES + 255) / 256;                       // 391
    const int edgeBlocks  = (N_EDGES + 255) / 256;                       // 4883
    const int placeBlocks = (int)(((long long)(N_EDGES / 4) * 8 + 255) / 256);  // 9766
    const int segBlocks   = (int)(((long long)N_NODES * 16 + 255) / 256);       // 6250

    k_zero<<<nodeBlocks, 256, 0, stream>>>(cnt);
    k_rank<<<edgeBlocks, 256, 0, stream>>>(ei, cnt, rank);
    k_gemm_norm<<<GEMM_BLOCKS, 256, 0, stream>>>(x, W, b, hn);
    k_scan1<<<nodeBlocks, 256, 0, stream>>>(cnt, rowptr, bsum);
    k_scan23<<<nodeBlocks, 256, 0, stream>>>(rowptr, bsum);
    k_edge_place<<<placeBlocks, 256, 0, stream>>>(hn, ei, rank, rowptr, out_w, srcs, wh);
    k_dis_y<<<segBlocks, 256, 0, stream>>>(rowptr, wh, mask, dis, y_a);

    // 5 APPNP steps in y-domain; last writes f to d_out
    k_spmv<<<segBlocks, 256, 0, stream>>>(rowptr, srcs, wh, y_a, dis, mask, alpha, y_b, out_f);
    k_spmv<<<segBlocks, 256, 0, stream>>>(rowptr, srcs, wh, y_b, dis, mask, alpha, y_a, out_f);
    k_spmv<<<segBlocks, 256, 0, stream>>>(rowptr, srcs, wh, y_a, dis, mask, alpha, y_b, out_f);
    k_spmv<<<segBlocks, 256, 0, stream>>>(rowptr, srcs, wh, y_b, dis, mask, alpha, y_a, out_f);
    k_spmv<<<segBlocks, 256, 0, stream>>>(rowptr, srcs, wh, y_a, dis, mask, alpha, y_b, out_f);
}